// Round 1
// baseline (68.541 us; speedup 1.0000x reference)
//
#include <hip/hip_runtime.h>
#include <hip/hip_bf16.h>

#define DD 256
#define SS 4096
#define LDK 264   // padded k-stride (bf16 elems): 264*2=528 B, 16B-aligned, bank-conflict-free

typedef __bf16 bf16x8 __attribute__((ext_vector_type(8)));
typedef float  f32x4  __attribute__((ext_vector_type(4)));

__device__ __forceinline__ float fast_tanh(float x) {
  // tanh(x) = 1 - 2/(exp(2x)+1); v_exp based, handles +-inf saturation naturally
  float e = __expf(2.0f * x);
  return 1.0f - 2.0f / (e + 1.0f);
}

// Kernel 1: logits[row] = sum_e tanh((x_row . W[:,e]) + b_e) * V_e
// 256 blocks x 1024 threads. Each block: 512 rows. Each wave: 32 rows (2 strips of 16).
__global__ __launch_bounds__(1024) void logits_kernel(
    const float* __restrict__ X, const float* __restrict__ W,
    const float* __restrict__ bias, const float* __restrict__ V,
    float* __restrict__ logits)
{
  __shared__ __bf16 Wt[DD * LDK];   // Wt[e][d] = W[d][e], bf16, padded stride
  __shared__ float  Vs[DD];
  __shared__ float  Bs[DD];

  const int t = threadIdx.x;
  // Stage W (coalesced fp32 reads, transposed bf16 writes; once per block)
  for (int idx = t; idx < DD * DD; idx += 1024) {
    int d = idx >> 8, e = idx & 255;
    Wt[e * LDK + d] = (__bf16)W[idx];
  }
  if (t < DD) { Vs[t] = V[t]; Bs[t] = bias[t]; }
  __syncthreads();

  const int wave = t >> 6, lane = t & 63;
  const int g  = lane >> 4;   // k-group 0..3
  const int lg = lane & 15;   // sub-lane 0..15
  const size_t rowBase = (size_t)blockIdx.x * 512 + (size_t)wave * 32;

  // A fragments: 2 strips x 8 k-steps, 8 bf16 each (lane: row=lg, k=ks*32+g*8+i)
  bf16x8 a[2][8];
  #pragma unroll
  for (int st = 0; st < 2; ++st) {
    const float* xr = X + (rowBase + st * 16 + lg) * DD;
    #pragma unroll
    for (int ks = 0; ks < 8; ++ks) {
      const float4* p = reinterpret_cast<const float4*>(xr + ks * 32 + g * 8);
      float4 f0 = p[0], f1 = p[1];
      bf16x8 fr;
      fr[0] = (__bf16)f0.x; fr[1] = (__bf16)f0.y; fr[2] = (__bf16)f0.z; fr[3] = (__bf16)f0.w;
      fr[4] = (__bf16)f1.x; fr[5] = (__bf16)f1.y; fr[6] = (__bf16)f1.z; fr[7] = (__bf16)f1.w;
      a[st][ks] = fr;
    }
  }

  float sp0[4] = {0.f,0.f,0.f,0.f};
  float sp1[4] = {0.f,0.f,0.f,0.f};

  #pragma unroll 1
  for (int n0 = 0; n0 < 16; ++n0) {
    const int col = n0 * 16 + lg;
    const __bf16* bp = Wt + col * LDK + g * 8;   // lane: n=col, k=ks*32+g*8+i (same k-order as A)
    f32x4 acc0 = {0.f,0.f,0.f,0.f};
    f32x4 acc1 = {0.f,0.f,0.f,0.f};
    #pragma unroll
    for (int ks = 0; ks < 8; ++ks) {
      bf16x8 bfr = *reinterpret_cast<const bf16x8*>(bp + ks * 32);
      acc0 = __builtin_amdgcn_mfma_f32_16x16x32_bf16(a[0][ks], bfr, acc0, 0, 0, 0);
      acc1 = __builtin_amdgcn_mfma_f32_16x16x32_bf16(a[1][ks], bfr, acc1, 0, 0, 0);
    }
    // C/D layout: col = lane&15 (= our col), row = g*4 + r  [m89-verified]
    const float vc = Vs[col], bc = Bs[col];
    #pragma unroll
    for (int r = 0; r < 4; ++r) {
      sp0[r] += fast_tanh(acc0[r] + bc) * vc;
      sp1[r] += fast_tanh(acc1[r] + bc) * vc;
    }
  }

  // Reduce over the 16 lanes (lg) holding different col-subsets of the same row
  #pragma unroll
  for (int m = 1; m < 16; m <<= 1) {
    #pragma unroll
    for (int r = 0; r < 4; ++r) {
      sp0[r] += __shfl_xor(sp0[r], m);
      sp1[r] += __shfl_xor(sp1[r], m);
    }
  }
  if (lg == 0) {
    #pragma unroll
    for (int r = 0; r < 4; ++r) {
      logits[rowBase + g * 4 + r]      = sp0[r];
      logits[rowBase + 16 + g * 4 + r] = sp1[r];
    }
  }
}

// Kernel 2: softmax over S per batch; in-place (attn overwrites logits). Also zeroes ctx.
__global__ __launch_bounds__(256) void softmax_kernel(
    const float* __restrict__ logits, float* __restrict__ attn, float* __restrict__ ctx)
{
  __shared__ float red[16];
  const int b = blockIdx.x, t = threadIdx.x;
  const float* lp = logits + (size_t)b * SS;

  float lv[16];
  float m = -1e30f;
  #pragma unroll
  for (int i = 0; i < 16; ++i) { lv[i] = lp[t + (i << 8)]; m = fmaxf(m, lv[i]); }
  #pragma unroll
  for (int off = 1; off < 64; off <<= 1) m = fmaxf(m, __shfl_xor(m, off));
  if ((t & 63) == 0) red[t >> 6] = m;
  __syncthreads();
  m = fmaxf(fmaxf(red[0], red[1]), fmaxf(red[2], red[3]));

  float sum = 0.f;
  #pragma unroll
  for (int i = 0; i < 16; ++i) { float e = __expf(lv[i] - m); lv[i] = e; sum += e; }
  #pragma unroll
  for (int off = 1; off < 64; off <<= 1) sum += __shfl_xor(sum, off);
  __syncthreads();
  if ((t & 63) == 0) red[8 + (t >> 6)] = sum;
  __syncthreads();
  sum = (red[8] + red[9]) + (red[10] + red[11]);

  const float inv = 1.0f / sum;
  #pragma unroll
  for (int i = 0; i < 16; ++i) attn[(size_t)b * SS + t + (i << 8)] = lv[i] * inv;

  ctx[b * DD + t] = 0.f;   // zero output for kernel 3's atomics
}

// Kernel 3: ctx[b,d] += sum_s attn[b,s] * x[b,s,d]. 1024 blocks (b x 32 s-chunks of 128).
__global__ __launch_bounds__(256) void context_kernel(
    const float* __restrict__ X, const float* __restrict__ attn, float* __restrict__ ctx)
{
  const int blk = blockIdx.x;
  const int b = blk >> 5, chunk = blk & 31;
  const int s0 = chunk << 7;
  const int t = threadIdx.x, q = t & 63, so = t >> 6;

  __shared__ float a_s[128];
  __shared__ float4 rs[256];

  if (t < 128) a_s[t] = attn[(size_t)b * SS + s0 + t];
  __syncthreads();

  const float4* Xp = reinterpret_cast<const float4*>(X + ((size_t)b * SS + s0) * DD);
  float4 acc = make_float4(0.f, 0.f, 0.f, 0.f);
  #pragma unroll 8
  for (int s = so; s < 128; s += 4) {
    const float w = a_s[s];
    const float4 xv = Xp[(size_t)s * 64 + q];
    acc.x = fmaf(w, xv.x, acc.x);
    acc.y = fmaf(w, xv.y, acc.y);
    acc.z = fmaf(w, xv.z, acc.z);
    acc.w = fmaf(w, xv.w, acc.w);
  }
  rs[t] = acc;
  __syncthreads();
  if (t < 64) {
    float4 a0 = rs[t], a1 = rs[t + 64], a2 = rs[t + 128], a3 = rs[t + 192];
    float sx = (a0.x + a1.x) + (a2.x + a3.x);
    float sy = (a0.y + a1.y) + (a2.y + a3.y);
    float sz = (a0.z + a1.z) + (a2.z + a3.z);
    float sw = (a0.w + a1.w) + (a2.w + a3.w);
    float* cp = ctx + b * DD + q * 4;
    atomicAdd(cp + 0, sx);
    atomicAdd(cp + 1, sy);
    atomicAdd(cp + 2, sz);
    atomicAdd(cp + 3, sw);
  }
}

extern "C" void kernel_launch(void* const* d_in, const int* in_sizes, int n_in,
                              void* d_out, int out_size, void* d_ws, size_t ws_size,
                              hipStream_t stream) {
  const float* X    = (const float*)d_in[0];  // [32,4096,256] fp32
  const float* W    = (const float*)d_in[1];  // [256,256]
  const float* bias = (const float*)d_in[2];  // [256]
  const float* V    = (const float*)d_in[3];  // [256,1]
  float* ctx = (float*)d_out;                 // [32,256]
  float* logits = (float*)d_ws;               // 131072 floats (512 KB); reused in-place as attn

  logits_kernel<<<256, 1024, 0, stream>>>(X, W, bias, V, logits);
  softmax_kernel<<<32, 256, 0, stream>>>(logits, logits, ctx);
  context_kernel<<<1024, 256, 0, stream>>>(X, logits, ctx);
}

// Round 2
// 62.666 us; speedup vs baseline: 1.0938x; 1.0938x over previous
//
#include <hip/hip_runtime.h>
#include <hip/hip_bf16.h>

#define DD 256
#define SS 4096
#define LDK 264   // padded k-stride (bf16 elems): 264*2=528 B, 16B-aligned

typedef __bf16 bf16x8 __attribute__((ext_vector_type(8)));
typedef float  f32x4  __attribute__((ext_vector_type(4)));

__device__ __forceinline__ float fast_tanh(float x) {
  float e = __expf(2.0f * x);
  return 1.0f - 2.0f / (e + 1.0f);
}

// Fused kernel: per block (512 rows = batch b, s-chunk of 512):
//   logits = tanh(x@W+b)@V  (MFMA, x rows held in registers as bf16 frags)
//   block-local softmax numerator: M_blk, S_blk = sum exp(l-M_blk),
//   P_blk[256] = sum_s exp(l_s - M_blk) * x_s   (from the SAME register frags)
// X is read from HBM exactly once.
__global__ __launch_bounds__(1024) void fused_kernel(
    const float* __restrict__ X, const float* __restrict__ W,
    const float* __restrict__ bias, const float* __restrict__ V,
    float* __restrict__ Pout, float* __restrict__ Mout, float* __restrict__ Sout)
{
  __shared__ __bf16 Wt[DD * LDK];     // 132 KB: Wt[e][d] = W[d][e]
  __shared__ float  Pacc[16][DD];     // 16 KB: per-wave partial context
  __shared__ float  Vs[DD];
  __shared__ float  Bs[DD];
  __shared__ float  wred[16];
  __shared__ float  sred[16];

  const int t = threadIdx.x;
  // Stage W transposed as bf16 (coalesced fp32 reads), once per block
  for (int idx = t; idx < DD * DD; idx += 1024) {
    int d = idx >> 8, e = idx & 255;
    Wt[e * LDK + d] = (__bf16)W[idx];
  }
  if (t < DD) { Vs[t] = V[t]; Bs[t] = bias[t]; }
  __syncthreads();

  const int wave = t >> 6, lane = t & 63;
  const int g  = lane >> 4;   // k-group 0..3
  const int lg = lane & 15;   // sub-lane 0..15
  const size_t rowBase = (size_t)blockIdx.x * 512 + (size_t)wave * 32;

  // ---- Phase 1: load A fragments (the only HBM read of X) ----
  bf16x8 a[2][8];   // [strip][k-step]; lane holds row st*16+lg, k = ks*32+g*8+i
  #pragma unroll
  for (int st = 0; st < 2; ++st) {
    const float* xr = X + (rowBase + st * 16 + lg) * DD;
    #pragma unroll
    for (int ks = 0; ks < 8; ++ks) {
      const float4* p = reinterpret_cast<const float4*>(xr + ks * 32 + g * 8);
      float4 f0 = p[0], f1 = p[1];
      bf16x8 fr;
      fr[0] = (__bf16)f0.x; fr[1] = (__bf16)f0.y; fr[2] = (__bf16)f0.z; fr[3] = (__bf16)f0.w;
      fr[4] = (__bf16)f1.x; fr[5] = (__bf16)f1.y; fr[6] = (__bf16)f1.z; fr[7] = (__bf16)f1.w;
      a[st][ks] = fr;
    }
  }

  // ---- Phase 2: MFMA over 16 col-tiles; tanh*V epilogue accumulates logits ----
  float sp0[4] = {0.f,0.f,0.f,0.f};
  float sp1[4] = {0.f,0.f,0.f,0.f};
  #pragma unroll 1
  for (int n0 = 0; n0 < 16; ++n0) {
    const int col = n0 * 16 + lg;
    const __bf16* bp = Wt + col * LDK + g * 8;   // same per-lane k-order as A
    f32x4 acc0 = {0.f,0.f,0.f,0.f};
    f32x4 acc1 = {0.f,0.f,0.f,0.f};
    #pragma unroll
    for (int ks = 0; ks < 8; ++ks) {
      bf16x8 bfr = *reinterpret_cast<const bf16x8*>(bp + ks * 32);
      acc0 = __builtin_amdgcn_mfma_f32_16x16x32_bf16(a[0][ks], bfr, acc0, 0, 0, 0);
      acc1 = __builtin_amdgcn_mfma_f32_16x16x32_bf16(a[1][ks], bfr, acc1, 0, 0, 0);
    }
    const float vc = Vs[col], bc = Bs[col];
    #pragma unroll
    for (int r = 0; r < 4; ++r) {          // C/D: col=lane&15, row=g*4+r
      sp0[r] += fast_tanh(acc0[r] + bc) * vc;
      sp1[r] += fast_tanh(acc1[r] + bc) * vc;
    }
  }

  // Reduce logit partials across the 16 lg-lanes (all lanes get the sum)
  #pragma unroll
  for (int m = 1; m < 16; m <<= 1) {
    #pragma unroll
    for (int r = 0; r < 4; ++r) {
      sp0[r] += __shfl_xor(sp0[r], m);
      sp1[r] += __shfl_xor(sp1[r], m);
    }
  }
  // Group g now holds logits of rows g*4+r (strip0) / 16+g*4+r (strip1), all lg.
  // Redistribute: lane (g,lg) needs rows lg and 16+lg -> src group lg>>2, elem lg&3.
  const int src = ((lg >> 2) << 4) | lg;
  float l0 = 0.f, l1 = 0.f;
  #pragma unroll
  for (int r = 0; r < 4; ++r) {
    float v0 = __shfl(sp0[r], src, 64);
    float v1 = __shfl(sp1[r], src, 64);
    if ((lg & 3) == r) { l0 = v0; l1 = v1; }
  }

  // ---- Phase 3: block-local softmax numerators ----
  // wave max over its 32 rows (l0,l1 depend only on lg -> 4 shfl levels)
  float wm = fmaxf(l0, l1);
  #pragma unroll
  for (int m = 1; m < 16; m <<= 1) wm = fmaxf(wm, __shfl_xor(wm, m));
  if (lane == 0) wred[wave] = wm;
  __syncthreads();
  float M = -1e30f;
  #pragma unroll
  for (int w = 0; w < 16; ++w) M = fmaxf(M, wred[w]);

  const float w0 = __expf(l0 - M);
  const float w1 = __expf(l1 - M);

  float se = w0 + w1;
  #pragma unroll
  for (int m = 1; m < 16; m <<= 1) se += __shfl_xor(se, m);
  if (lane == 0) sred[wave] = se;

  // Partial weighted sum from register fragments: p[ks*8+i] covers col ks*32+g*8+i
  float p[64];
  #pragma unroll
  for (int ks = 0; ks < 8; ++ks)
    #pragma unroll
    for (int i = 0; i < 8; ++i)
      p[ks * 8 + i] = w0 * (float)a[0][ks][i] + w1 * (float)a[1][ks][i];
  #pragma unroll
  for (int m = 1; m < 16; m <<= 1) {
    #pragma unroll
    for (int j = 0; j < 64; ++j) p[j] += __shfl_xor(p[j], m);
  }
  if (lg == 0) {   // lanes 0,16,32,48 each own cols g*8..g*8+7 per ks
    #pragma unroll
    for (int ks = 0; ks < 8; ++ks) {
      float4* dst = reinterpret_cast<float4*>(&Pacc[wave][ks * 32 + g * 8]);
      dst[0] = make_float4(p[ks*8+0], p[ks*8+1], p[ks*8+2], p[ks*8+3]);
      dst[1] = make_float4(p[ks*8+4], p[ks*8+5], p[ks*8+6], p[ks*8+7]);
    }
  }
  __syncthreads();

  // ---- Phase 4: cross-wave reduce + write per-block partials ----
  if (t < DD) {
    float s = 0.f;
    #pragma unroll
    for (int w = 0; w < 16; ++w) s += Pacc[w][t];
    Pout[(size_t)blockIdx.x * DD + t] = s;
  }
  if (t == 0) {
    float ss = 0.f;
    #pragma unroll
    for (int w = 0; w < 16; ++w) ss += sred[w];
    Sout[blockIdx.x] = ss;
    Mout[blockIdx.x] = M;
  }
}

// Combine: per batch, merge the 8 block partials with max-rescale.
__global__ __launch_bounds__(256) void combine_kernel(
    const float* __restrict__ P, const float* __restrict__ Mb,
    const float* __restrict__ Sb, float* __restrict__ ctx)
{
  const int b = blockIdx.x, t = threadIdx.x;
  float Mg = -1e30f;
  #pragma unroll
  for (int k = 0; k < 8; ++k) Mg = fmaxf(Mg, Mb[b * 8 + k]);
  float denom = 0.f, acc = 0.f;
  #pragma unroll
  for (int k = 0; k < 8; ++k) {
    const float f = __expf(Mb[b * 8 + k] - Mg);
    denom += f * Sb[b * 8 + k];
    acc   += f * P[(size_t)(b * 8 + k) * DD + t];
  }
  ctx[b * DD + t] = acc / denom;
}

extern "C" void kernel_launch(void* const* d_in, const int* in_sizes, int n_in,
                              void* d_out, int out_size, void* d_ws, size_t ws_size,
                              hipStream_t stream) {
  const float* X    = (const float*)d_in[0];  // [32,4096,256] fp32
  const float* W    = (const float*)d_in[1];  // [256,256]
  const float* bias = (const float*)d_in[2];  // [256]
  const float* V    = (const float*)d_in[3];  // [256,1]
  float* ctx = (float*)d_out;                 // [32,256]

  float* P = (float*)d_ws;                    // [256,256] block partials
  float* M = P + 256 * DD;                    // [256]
  float* S = M + 256;                         // [256]

  fused_kernel<<<256, 1024, 0, stream>>>(X, W, bias, V, P, M, S);
  combine_kernel<<<32, 256, 0, stream>>>(P, M, S, ctx);
}

// Round 3
// 51.958 us; speedup vs baseline: 1.3192x; 1.2061x over previous
//
#include <hip/hip_runtime.h>
#include <hip/hip_bf16.h>

#define DD 256
#define SS 4096
#define LDK 264   // padded k-stride (bf16 elems): 264*2=528 B, 16B-aligned

typedef __bf16 bf16x8 __attribute__((ext_vector_type(8)));
typedef float  f32x4  __attribute__((ext_vector_type(4)));

__device__ __forceinline__ float fast_tanh(float x) {
  float e = __expf(2.0f * x);
  return 1.0f - 2.0f / (e + 1.0f);
}

// DPP-based add over 16-lane rows (reduces across lg=lane&15 within each g-group)
template<int CTRL>
__device__ __forceinline__ float dpp_add(float v) {
  int y = __builtin_amdgcn_update_dpp(0, __float_as_int(v), CTRL, 0xF, 0xF, true);
  return v + __int_as_float(y);
}
__device__ __forceinline__ float row16_sum(float v) {
  v = dpp_add<0xB1>(v);    // quad_perm [1,0,3,2]  (xor 1)
  v = dpp_add<0x4E>(v);    // quad_perm [2,3,0,1]  (xor 2)
  v = dpp_add<0x124>(v);   // row_ror:4
  v = dpp_add<0x128>(v);   // row_ror:8
  return v;                // all 16 lanes of the row hold the sum
}

// Fused kernel: per block (512 rows = batch b, s-chunk of 512):
//   logits = tanh(x@W+b)@V  (MFMA, x rows held in registers as bf16 frags)
//   block-local softmax: M_blk, S_blk, P_blk[256] = sum_s exp(l_s-M_blk)*x_s
// X is read from HBM exactly once.
__global__ __launch_bounds__(1024, 1) void fused_kernel(
    const float* __restrict__ X, const float* __restrict__ W,
    const float* __restrict__ bias, const float* __restrict__ V,
    float* __restrict__ Pout, float* __restrict__ Mout, float* __restrict__ Sout)
{
  __shared__ __bf16 Wt[DD * LDK];     // 132 KB: Wt[e][d] = W[d][e]
  __shared__ float  Pacc[16][DD];     // 16 KB: per-wave partial context
  __shared__ float  Vs[DD];
  __shared__ float  Bs[DD];
  __shared__ float  wred[16];
  __shared__ float  sred[16];

  const int t = threadIdx.x;
  // Stage W transposed as bf16 (coalesced fp32 reads), once per block
  for (int idx = t; idx < DD * DD; idx += 1024) {
    int d = idx >> 8, e = idx & 255;
    Wt[e * LDK + d] = (__bf16)W[idx];
  }
  if (t < DD) { Vs[t] = V[t]; Bs[t] = bias[t]; }
  __syncthreads();

  const int wave = t >> 6, lane = t & 63;
  const int g  = lane >> 4;   // k-group 0..3 (DPP row index)
  const int lg = lane & 15;   // sub-lane 0..15 (within DPP row)
  const size_t rowBase = (size_t)blockIdx.x * 512 + (size_t)wave * 32;

  // ---- Phase 1: load A fragments (the only HBM read of X) ----
  bf16x8 a[2][8];   // [strip][k-step]; lane holds row st*16+lg, k = ks*32+g*8+i
  #pragma unroll
  for (int st = 0; st < 2; ++st) {
    const float* xr = X + (rowBase + st * 16 + lg) * DD;
    #pragma unroll
    for (int ks = 0; ks < 8; ++ks) {
      const float4* p = reinterpret_cast<const float4*>(xr + ks * 32 + g * 8);
      float4 f0 = p[0], f1 = p[1];
      bf16x8 fr;
      fr[0] = (__bf16)f0.x; fr[1] = (__bf16)f0.y; fr[2] = (__bf16)f0.z; fr[3] = (__bf16)f0.w;
      fr[4] = (__bf16)f1.x; fr[5] = (__bf16)f1.y; fr[6] = (__bf16)f1.z; fr[7] = (__bf16)f1.w;
      a[st][ks] = fr;
    }
  }

  // ---- Phase 2: MFMA over 16 col-tiles; tanh*V epilogue accumulates logits ----
  float sp0[4] = {0.f,0.f,0.f,0.f};
  float sp1[4] = {0.f,0.f,0.f,0.f};
  #pragma unroll 1
  for (int n0 = 0; n0 < 16; ++n0) {
    const int col = n0 * 16 + lg;
    const __bf16* bp = Wt + col * LDK + g * 8;   // same per-lane k-order as A
    f32x4 acc0 = {0.f,0.f,0.f,0.f};
    f32x4 acc1 = {0.f,0.f,0.f,0.f};
    #pragma unroll
    for (int ks = 0; ks < 8; ++ks) {
      bf16x8 bfr = *reinterpret_cast<const bf16x8*>(bp + ks * 32);
      acc0 = __builtin_amdgcn_mfma_f32_16x16x32_bf16(a[0][ks], bfr, acc0, 0, 0, 0);
      acc1 = __builtin_amdgcn_mfma_f32_16x16x32_bf16(a[1][ks], bfr, acc1, 0, 0, 0);
    }
    const float vc = Vs[col], bc = Bs[col];
    #pragma unroll
    for (int r = 0; r < 4; ++r) {          // C/D: col=lane&15, row=g*4+r
      sp0[r] += fast_tanh(acc0[r] + bc) * vc;
      sp1[r] += fast_tanh(acc1[r] + bc) * vc;
    }
  }

  // Reduce logit partials across the 16 lg-lanes (all lanes get the sum)
  #pragma unroll
  for (int m = 1; m < 16; m <<= 1) {
    #pragma unroll
    for (int r = 0; r < 4; ++r) {
      sp0[r] += __shfl_xor(sp0[r], m);
      sp1[r] += __shfl_xor(sp1[r], m);
    }
  }
  // Group g holds logits of rows g*4+r (strip0) / 16+g*4+r (strip1), all lg.
  // Redistribute: lane (g,lg) needs rows lg and 16+lg -> src group lg>>2, elem lg&3.
  const int src = ((lg >> 2) << 4) | lg;
  float l0 = 0.f, l1 = 0.f;
  #pragma unroll
  for (int r = 0; r < 4; ++r) {
    float v0 = __shfl(sp0[r], src, 64);
    float v1 = __shfl(sp1[r], src, 64);
    if ((lg & 3) == r) { l0 = v0; l1 = v1; }
  }

  // ---- Phase 3: block-local softmax numerators ----
  float wm = fmaxf(l0, l1);
  #pragma unroll
  for (int m = 1; m < 16; m <<= 1) wm = fmaxf(wm, __shfl_xor(wm, m));
  if (lane == 0) wred[wave] = wm;
  __syncthreads();
  float M = -1e30f;
  #pragma unroll
  for (int w = 0; w < 16; ++w) M = fmaxf(M, wred[w]);

  const float w0 = __expf(l0 - M);
  const float w1 = __expf(l1 - M);

  float se = w0 + w1;
  #pragma unroll
  for (int m = 1; m < 16; m <<= 1) se += __shfl_xor(se, m);
  if (lane == 0) sred[wave] = se;

  // Weighted partial sums: for each ks, p8[i] covers d = ks*32+g*8+i.
  // DPP row-reduce sums over the 16 lg-lanes (rows st*16+lg); lanes lg<2
  // write the 8 results (disjoint d per (ks,g)) to Pacc[wave].
  #pragma unroll
  for (int ks = 0; ks < 8; ++ks) {
    float p8[8];
    #pragma unroll
    for (int i = 0; i < 8; ++i)
      p8[i] = w0 * (float)a[0][ks][i] + w1 * (float)a[1][ks][i];
    #pragma unroll
    for (int i = 0; i < 8; ++i) p8[i] = row16_sum(p8[i]);
    if (lg < 2) {
      float4 v = (lg == 0) ? make_float4(p8[0], p8[1], p8[2], p8[3])
                           : make_float4(p8[4], p8[5], p8[6], p8[7]);
      *reinterpret_cast<float4*>(&Pacc[wave][ks * 32 + g * 8 + lg * 4]) = v;
    }
  }
  __syncthreads();

  // ---- Phase 4: cross-wave reduce + write per-block partials ----
  if (t < DD) {
    float s = 0.f;
    #pragma unroll
    for (int w = 0; w < 16; ++w) s += Pacc[w][t];
    Pout[(size_t)blockIdx.x * DD + t] = s;
  }
  if (t == 0) {
    float ss = 0.f;
    #pragma unroll
    for (int w = 0; w < 16; ++w) ss += sred[w];
    Sout[blockIdx.x] = ss;
    Mout[blockIdx.x] = M;
  }
}

// Combine: per batch, merge the 8 block partials with max-rescale.
__global__ __launch_bounds__(256) void combine_kernel(
    const float* __restrict__ P, const float* __restrict__ Mb,
    const float* __restrict__ Sb, float* __restrict__ ctx)
{
  const int b = blockIdx.x, t = threadIdx.x;
  float Mg = -1e30f;
  #pragma unroll
  for (int k = 0; k < 8; ++k) Mg = fmaxf(Mg, Mb[b * 8 + k]);
  float denom = 0.f, acc = 0.f;
  #pragma unroll
  for (int k = 0; k < 8; ++k) {
    const float f = __expf(Mb[b * 8 + k] - Mg);
    denom += f * Sb[b * 8 + k];
    acc   += f * P[(size_t)(b * 8 + k) * DD + t];
  }
  ctx[b * DD + t] = acc / denom;
}

extern "C" void kernel_launch(void* const* d_in, const int* in_sizes, int n_in,
                              void* d_out, int out_size, void* d_ws, size_t ws_size,
                              hipStream_t stream) {
  const float* X    = (const float*)d_in[0];  // [32,4096,256] fp32
  const float* W    = (const float*)d_in[1];  // [256,256]
  const float* bias = (const float*)d_in[2];  // [256]
  const float* V    = (const float*)d_in[3];  // [256,1]
  float* ctx = (float*)d_out;                 // [32,256]

  float* P = (float*)d_ws;                    // [256,256] block partials
  float* M = P + 256 * DD;                    // [256]
  float* S = M + 256;                         // [256]

  fused_kernel<<<256, 1024, 0, stream>>>(X, W, bias, V, P, M, S);
  combine_kernel<<<32, 256, 0, stream>>>(P, M, S, ctx);
}

// Round 4
// 51.445 us; speedup vs baseline: 1.3323x; 1.0100x over previous
//
#include <hip/hip_runtime.h>
#include <hip/hip_bf16.h>

#define DD 256
#define SS 4096

typedef __bf16 bf16x8 __attribute__((ext_vector_type(8)));
typedef float  f32x4  __attribute__((ext_vector_type(4)));

__device__ __forceinline__ float fast_tanh(float x) {
  float e = __expf(2.0f * x);
  return 1.0f - 2.0f / (e + 1.0f);
}

// DPP helpers: reduce across the 16-lane row (lg = lane&15) within each g-group
template<int CTRL>
__device__ __forceinline__ float dpp_mov(float v) {
  return __int_as_float(__builtin_amdgcn_update_dpp(0, __float_as_int(v), CTRL, 0xF, 0xF, true));
}
__device__ __forceinline__ float row16_sum(float v) {
  v += dpp_mov<0xB1>(v);   // quad_perm xor1
  v += dpp_mov<0x4E>(v);   // quad_perm xor2
  v += dpp_mov<0x124>(v);  // row_ror:4
  v += dpp_mov<0x128>(v);  // row_ror:8
  return v;
}
__device__ __forceinline__ float row16_max(float v) {
  v = fmaxf(v, dpp_mov<0xB1>(v));
  v = fmaxf(v, dpp_mov<0x4E>(v));
  v = fmaxf(v, dpp_mov<0x124>(v));
  v = fmaxf(v, dpp_mov<0x128>(v));
  return v;
}

// Fused kernel: per block (512 rows = batch b, s-chunk of 512):
//   logits = tanh(x@W+b)@V  (MFMA, x rows held in registers as bf16 frags)
//   block-local softmax: M_blk, S_blk, P_blk[256] = sum_s exp(l_s-M_blk)*x_s
// X is read from HBM exactly once.
__global__ __launch_bounds__(1024, 1) __attribute__((amdgpu_waves_per_eu(4)))
void fused_kernel(
    const float* __restrict__ X, const float* __restrict__ W,
    const float* __restrict__ bias, const float* __restrict__ V,
    float* __restrict__ Pout, float* __restrict__ Mout, float* __restrict__ Sout)
{
  // Fragment-order W: chunk c = ((n0*8+ks)*64 + lane) holds 8 bf16:
  //   W[ks*32 + (lane>>4)*8 + i][n0*16 + (lane&15)], i=0..7
  // Phase-2 read is contiguous 16B/lane -> conflict-free ds_read_b128.
  __shared__ __bf16 WtF[8192 * 8];    // 128 KB
  __shared__ float  Pacc[16][DD];     // 16 KB
  __shared__ float  Vs[DD];
  __shared__ float  Bs[DD];
  __shared__ float  wred[16];
  __shared__ float  sred[16];

  const int t = threadIdx.x;
  // Stage W in fragment order: 8 chunks per thread, 8-dword gather + b128 write
  for (int c = t; c < 8192; c += 1024) {
    const int lane_c = c & 63;
    const int ks  = (c >> 6) & 7;
    const int n0  = c >> 9;
    const int col = n0 * 16 + (lane_c & 15);
    const int k0  = ks * 32 + (lane_c >> 4) * 8;
    const float* wp = W + k0 * DD + col;
    bf16x8 fr;
    #pragma unroll
    for (int i = 0; i < 8; ++i) fr[i] = (__bf16)wp[i * DD];
    *reinterpret_cast<bf16x8*>(&WtF[(size_t)c * 8]) = fr;
  }
  if (t < DD) { Vs[t] = V[t]; Bs[t] = bias[t]; }
  __syncthreads();

  const int wave = t >> 6, lane = t & 63;
  const int g  = lane >> 4;   // k-group 0..3 (DPP row index)
  const int lg = lane & 15;   // sub-lane 0..15
  const size_t rowBase = (size_t)blockIdx.x * 512 + (size_t)wave * 32;

  // ---- Phase 1: load A fragments (the only HBM read of X) ----
  bf16x8 a[2][8];   // [strip][k-step]; lane holds row st*16+lg, k = ks*32+g*8+i
  #pragma unroll
  for (int st = 0; st < 2; ++st) {
    const float* xr = X + (rowBase + st * 16 + lg) * DD;
    #pragma unroll
    for (int ks = 0; ks < 8; ++ks) {
      const float4* p = reinterpret_cast<const float4*>(xr + ks * 32 + g * 8);
      float4 f0 = p[0], f1 = p[1];
      bf16x8 fr;
      fr[0] = (__bf16)f0.x; fr[1] = (__bf16)f0.y; fr[2] = (__bf16)f0.z; fr[3] = (__bf16)f0.w;
      fr[4] = (__bf16)f1.x; fr[5] = (__bf16)f1.y; fr[6] = (__bf16)f1.z; fr[7] = (__bf16)f1.w;
      a[st][ks] = fr;
    }
  }

  // ---- Phase 2: MFMA over 16 col-tiles; tanh*V epilogue accumulates logits ----
  float sp0[4] = {0.f,0.f,0.f,0.f};
  float sp1[4] = {0.f,0.f,0.f,0.f};
  #pragma unroll 1
  for (int n0 = 0; n0 < 16; ++n0) {
    const __bf16* bp = WtF + ((size_t)(n0 * 8) * 64 + lane) * 8;
    f32x4 acc0 = {0.f,0.f,0.f,0.f};
    f32x4 acc1 = {0.f,0.f,0.f,0.f};
    #pragma unroll
    for (int ks = 0; ks < 8; ++ks) {
      bf16x8 bfr = *reinterpret_cast<const bf16x8*>(bp + (size_t)ks * 64 * 8);
      acc0 = __builtin_amdgcn_mfma_f32_16x16x32_bf16(a[0][ks], bfr, acc0, 0, 0, 0);
      acc1 = __builtin_amdgcn_mfma_f32_16x16x32_bf16(a[1][ks], bfr, acc1, 0, 0, 0);
    }
    const int col = n0 * 16 + lg;
    const float vc = Vs[col], bc = Bs[col];
    #pragma unroll
    for (int r = 0; r < 4; ++r) {          // C/D: col=lane&15, row=g*4+r
      sp0[r] += fast_tanh(acc0[r] + bc) * vc;
      sp1[r] += fast_tanh(acc1[r] + bc) * vc;
    }
  }

  // Reduce logit partials across the 16 lg-lanes (DPP, all lanes get the sum)
  #pragma unroll
  for (int r = 0; r < 4; ++r) { sp0[r] = row16_sum(sp0[r]); sp1[r] = row16_sum(sp1[r]); }

  // Group g holds logits of rows g*4+r (strip0) / 16+g*4+r (strip1), all lg.
  // Redistribute: lane (g,lg) needs rows lg and 16+lg -> src group lg>>2, elem lg&3.
  const int src = ((lg >> 2) << 4) | lg;
  float l0 = 0.f, l1 = 0.f;
  #pragma unroll
  for (int r = 0; r < 4; ++r) {
    float v0 = __shfl(sp0[r], src, 64);
    float v1 = __shfl(sp1[r], src, 64);
    if ((lg & 3) == r) { l0 = v0; l1 = v1; }
  }

  // ---- Phase 3: block-local softmax numerators ----
  float wm = row16_max(fmaxf(l0, l1));   // l0,l1 depend only on lg
  if (lane == 0) wred[wave] = wm;
  __syncthreads();
  float M = -1e30f;
  #pragma unroll
  for (int w = 0; w < 16; ++w) M = fmaxf(M, wred[w]);

  const float w0 = __expf(l0 - M);
  const float w1 = __expf(l1 - M);

  float se = row16_sum(w0 + w1);
  if (lane == 0) sred[wave] = se;

  // Weighted partial sums: for each ks, p8[i] covers d = ks*32+g*8+i.
  // DPP row-reduce over the 16 lg-lanes; lanes lg<2 write float4s (disjoint banks).
  #pragma unroll
  for (int ks = 0; ks < 8; ++ks) {
    float p8[8];
    #pragma unroll
    for (int i = 0; i < 8; ++i)
      p8[i] = w0 * (float)a[0][ks][i] + w1 * (float)a[1][ks][i];
    #pragma unroll
    for (int i = 0; i < 8; ++i) p8[i] = row16_sum(p8[i]);
    if (lg < 2) {
      float4 v = (lg == 0) ? make_float4(p8[0], p8[1], p8[2], p8[3])
                           : make_float4(p8[4], p8[5], p8[6], p8[7]);
      *reinterpret_cast<float4*>(&Pacc[wave][ks * 32 + g * 8 + lg * 4]) = v;
    }
  }
  __syncthreads();

  // ---- Phase 4: cross-wave reduce + write per-block partials ----
  if (t < DD) {
    float s = 0.f;
    #pragma unroll
    for (int w = 0; w < 16; ++w) s += Pacc[w][t];
    Pout[(size_t)blockIdx.x * DD + t] = s;
  }
  if (t == 0) {
    float ss = 0.f;
    #pragma unroll
    for (int w = 0; w < 16; ++w) ss += sred[w];
    Sout[blockIdx.x] = ss;
    Mout[blockIdx.x] = M;
  }
}

// Combine: per batch, merge the 8 block partials with max-rescale.
__global__ __launch_bounds__(256) void combine_kernel(
    const float* __restrict__ P, const float* __restrict__ Mb,
    const float* __restrict__ Sb, float* __restrict__ ctx)
{
  const int b = blockIdx.x, t = threadIdx.x;
  float Mg = -1e30f;
  #pragma unroll
  for (int k = 0; k < 8; ++k) Mg = fmaxf(Mg, Mb[b * 8 + k]);
  float denom = 0.f, acc = 0.f;
  #pragma unroll
  for (int k = 0; k < 8; ++k) {
    const float f = __expf(Mb[b * 8 + k] - Mg);
    denom += f * Sb[b * 8 + k];
    acc   += f * P[(size_t)(b * 8 + k) * DD + t];
  }
  ctx[b * DD + t] = acc / denom;
}

extern "C" void kernel_launch(void* const* d_in, const int* in_sizes, int n_in,
                              void* d_out, int out_size, void* d_ws, size_t ws_size,
                              hipStream_t stream) {
  const float* X    = (const float*)d_in[0];  // [32,4096,256] fp32
  const float* W    = (const float*)d_in[1];  // [256,256]
  const float* bias = (const float*)d_in[2];  // [256]
  const float* V    = (const float*)d_in[3];  // [256,1]
  float* ctx = (float*)d_out;                 // [32,256]

  float* P = (float*)d_ws;                    // [256,256] block partials
  float* M = P + 256 * DD;                    // [256]
  float* S = M + 256;                         // [256]

  fused_kernel<<<256, 1024, 0, stream>>>(X, W, bias, V, P, M, S);
  combine_kernel<<<32, 256, 0, stream>>>(P, M, S, ctx);
}